// Round 1
// baseline (735.356 us; speedup 1.0000x reference)
//
#include <hip/hip_runtime.h>

// Temporal-biased random-walk sampler, bit-exact replication of the JAX
// reference (threefry2x32 + Gumbel argmax). See session notes: the checker
// demands argmax-exact reproduction, so all f32 math mirrors XLA-CPU's
// Cephes-style expf/logf and JAX's partitionable threefry bit layout.

// 1 = JAX >= 0.5.0 default (jax_threefry_partitionable=True):
//     bits[j] = o0 ^ o1 of threefry2x32(key, (0, j))
// 0 = legacy layout: iota split in halves, j<h -> o0 of (j, j+h), else o1 of (j-h, j)
#define PRNG_PARTITIONABLE 1

#define W_WALKS 10
#define L_LEN   10

__device__ __forceinline__ unsigned rotl32(unsigned v, unsigned r) {
  return (v << r) | (v >> (32u - r));
}

// Threefry-2x32, 20 rounds, matching jax/_src/prng.py _threefry2x32_lowering.
__device__ __forceinline__ void tf2x32(unsigned k0, unsigned k1,
                                       unsigned x0, unsigned x1,
                                       unsigned &o0, unsigned &o1) {
  const unsigned ks2 = 0x1BD11BDAu ^ k0 ^ k1;
  x0 += k0; x1 += k1;
#define TF_R(r) { x0 += x1; x1 = rotl32(x1, (r)) ^ x0; }
  TF_R(13) TF_R(15) TF_R(26) TF_R(6)
  x0 += k1;  x1 += ks2 + 1u;
  TF_R(17) TF_R(29) TF_R(16) TF_R(24)
  x0 += ks2; x1 += k0 + 2u;
  TF_R(13) TF_R(15) TF_R(26) TF_R(6)
  x0 += k0;  x1 += k1 + 3u;
  TF_R(17) TF_R(29) TF_R(16) TF_R(24)
  x0 += k1;  x1 += ks2 + 4u;
  TF_R(13) TF_R(15) TF_R(26) TF_R(6)
  x0 += ks2; x1 += k0 + 5u;
#undef TF_R
  o0 = x0; o1 = x1;
}

// expf replica of XLA-CPU llvm_ir_runtime GenerateVF32Exp (Cephes/Eigen).
// Rounding-locked intrinsics so hipcc contraction cannot change results.
__device__ __forceinline__ float xla_expf(float input) {
  float x = fminf(fmaxf(input, -88.3762626647949f), 88.3762626647950f);
  float fx = floorf(__fmaf_rn(x, 1.44269504088896341f, 0.5f));
  float tmp = __fmul_rn(0.693359375f, fx);
  float z   = __fmul_rn(-2.12194440e-4f, fx);
  float xx  = __fsub_rn(x, tmp);
  xx = __fsub_rn(xx, z);
  float z2 = __fmul_rn(xx, xx);
  float y = __fmaf_rn(xx, 1.9875691500E-4f, 1.3981999507E-3f);
  y = __fmaf_rn(y, xx, 8.3334519073E-3f);
  y = __fmaf_rn(y, xx, 4.1665795894E-2f);
  y = __fmaf_rn(y, xx, 1.6666665459E-1f);
  y = __fmaf_rn(y, xx, 5.0000001201E-1f);
  y = __fmaf_rn(y, z2, xx);
  y = __fadd_rn(y, 1.0f);
  int emm0 = (int)fx;                       // FPToSI; fx integral in [-128,128]
  float two_m = __uint_as_float((unsigned)((emm0 + 0x7f) << 23));
  return fmaxf(__fmul_rn(y, two_m), input); // no-op in our domain, mirrors XLA
}

// logf replica of XLA-CPU GenerateVF32Log (Cephes/Eigen), branchless mantissa
// split exactly as XLA emits it: x = (x - 1) + (mask ? x : 0).
__device__ __forceinline__ float xla_logf(float input) {
  float t0 = fmaxf(input, 1.17549435e-38f);   // min normal, cuts denormals
  unsigned ux = __float_as_uint(t0);
  int emm0 = (int)(ux >> 23) - 0x7f;
  float x = __uint_as_float((ux & 0x807fffffu) | 0x3f000000u); // [0.5, 1)
  float e = __fadd_rn((float)emm0, 1.0f);
  bool m = x < 0.707106781186547524f;
  float xm = m ? x : 0.0f;
  float em = m ? 1.0f : 0.0f;
  e = __fsub_rn(e, em);
  x = __fsub_rn(x, 1.0f);
  x = __fadd_rn(x, xm);
  float z = __fmul_rn(x, x);
  float y = __fmaf_rn(7.0376836292E-2f, x, -1.1514610310E-1f);
  y = __fmaf_rn(y, x, 1.1676998740E-1f);
  y = __fmaf_rn(y, x, -1.2420140846E-1f);
  y = __fmaf_rn(y, x, 1.4249322787E-1f);
  y = __fmaf_rn(y, x, -1.6668057665E-1f);
  y = __fmaf_rn(y, x, 2.0000714765E-1f);
  y = __fmaf_rn(y, x, -2.4999993993E-1f);
  y = __fmaf_rn(y, x, 3.3333331174E-1f);
  y = __fmul_rn(y, x);
  y = __fmul_rn(y, z);
  y = __fmaf_rn(e, -2.12194440e-4f, y);
  y = __fmaf_rn(-0.5f, z, y);
  x = __fadd_rn(x, y);
  x = __fmaf_rn(e, 0.693359375f, x);
  return x;
}

// g = -log(-log(u)), u from one 32-bit threefry draw, matching jax.random.gumbel.
__device__ __forceinline__ float gumbel_from_bits(unsigned bits) {
  float f = __fsub_rn(__uint_as_float((bits >> 9) | 0x3f800000u), 1.0f); // [0,1)
  float u = fmaxf(1.17549435e-38f, __fadd_rn(f, 1.17549435e-38f));
  return -xla_logf(-xla_logf(u));
}

__global__ __launch_bounds__(256)
void walk_kernel(const int* __restrict__ src_nodes,
                 const float* __restrict__ cur_times,
                 const int* __restrict__ nb_ids,
                 const float* __restrict__ nb_times,
                 float* __restrict__ out,      // [nodes | times | masks], each B*W*L
                 int total /* B*W */, int bwl /* B*W*L */) {
  int tid = blockIdx.x * blockDim.x + threadIdx.x;
  if (tid >= total) return;

  const int b = tid / W_WALKS;
  float* out_nodes = out;
  float* out_times = out + bwl;
  float* out_masks = out + 2 * bwl;

  int   cn    = src_nodes[b];
  float ctime = cur_times[b];
  bool  alive = true;

  const int obase = tid * L_LEN;
  out_nodes[obase] = (float)cn;
  out_times[obase] = ctime;
  out_masks[obase] = 1.0f;

  const unsigned h = (unsigned)(total * 64) >> 1;  // legacy layout half-size

  for (int step = 1; step < L_LEN; ++step) {
    if (alive) {
      // kstep = fold_in(key(42), step) = threefry2x32([0,42],[0,step])
      unsigned k0, k1;
      tf2x32(0u, 42u, 0u, (unsigned)step, k0, k1);

      const float* trow = nb_times + (size_t)cn * 64;
      const int*   irow = nb_ids   + (size_t)cn * 64;

      // pass 1: t_max over ALL 64 (order-exact), masked-weight sum (sequential,
      // denominator is common-mode so order is non-critical), has_valid.
      float tmax = trow[0];
      for (int d = 1; d < 64; ++d) tmax = fmaxf(tmax, trow[d]);
      float tmax2 = (tmax > 0.0f) ? tmax : 1.0f;

      bool  havalid = false;
      float sum = 0.0f;
      for (int d = 0; d < 64; ++d) {
        float t = trow[d];
        bool  valid = (t < ctime);
        havalid |= valid;
        float wv = valid ? xla_expf(__fdiv_rn(__fsub_rn(t, tmax2), 0.1f)) : 0.0f;
        sum = __fadd_rn(sum, wv);
      }
      float denom = __fadd_rn(sum, 1e-10f);

      // pass 2: score_d = log(w_d/denom + eps) + gumbel_d ; first-max argmax.
      float best = -3.402823466e38f;
      int   bidx = 0;
      for (int d = 0; d < 64; ++d) {
        float t = trow[d];
        bool  valid = (t < ctime);
        float wv = valid ? xla_expf(__fdiv_rn(__fsub_rn(t, tmax2), 0.1f)) : 0.0f;
        float p  = __fdiv_rn(wv, denom);
        float lp = xla_logf(__fadd_rn(p, 1e-10f));

        unsigned j = (unsigned)(tid * 64 + d);   // flat index into (B,W,64)
        unsigned o0, o1, bits;
#if PRNG_PARTITIONABLE
        tf2x32(k0, k1, 0u, j, o0, o1);
        bits = o0 ^ o1;
#else
        if (j < h) { tf2x32(k0, k1, j, j + h, o0, o1); bits = o0; }
        else       { tf2x32(k0, k1, j - h, j, o0, o1); bits = o1; }
#endif
        float s = __fadd_rn(lp, gumbel_from_bits(bits));
        if (s > best) { best = s; bidx = d; }   // strict > == first-occurrence argmax
      }

      if (!havalid) {
        alive = false;                // sticky termination, node/time frozen
      } else {
        cn    = irow[bidx];
        ctime = trow[bidx];
      }
    }
    out_nodes[obase + step] = (float)cn;
    out_times[obase + step] = ctime;
    out_masks[obase + step] = alive ? 1.0f : 0.0f;
  }
}

extern "C" void kernel_launch(void* const* d_in, const int* in_sizes, int n_in,
                              void* d_out, int out_size, void* d_ws, size_t ws_size,
                              hipStream_t stream) {
  const int*   src_nodes = (const int*)d_in[0];
  const float* cur_times = (const float*)d_in[1];
  const int*   nb_ids    = (const int*)d_in[2];
  const float* nb_times  = (const float*)d_in[3];
  // d_in[4] = num_walks (10), d_in[5] = walk_length (10) — fixed by setup_inputs.

  const int B     = in_sizes[0];
  const int total = B * W_WALKS;           // 81920 walks
  const int bwl   = out_size / 3;          // B*W*L per output tensor

  float* out = (float*)d_out;

  const int block = 256;
  const int grid  = (total + block - 1) / block;
  walk_kernel<<<grid, block, 0, stream>>>(src_nodes, cur_times, nb_ids, nb_times,
                                          out, total, bwl);
}